// Round 3
// baseline (304.153 us; speedup 1.0000x reference)
//
#include <hip/hip_runtime.h>

#define BB 4
#define NN 10000
#define MM 10000
#define PP 128
#define KS 32
#define KSC 4
#define ZZ 128

// workspace layout in floats (all offsets 16B-aligned)
#define OFF_PN 0                       // packed noisy  [B][N][4] (x,y,z,|p|^2)
#define OFF_PC (OFF_PN + BB*NN*4)      // packed clean  [B][M][4] (x,y,z,|c|^2)
#define OFF_FO (OFF_PC + BB*MM*4)      // f_origin      [B][P][4]
#define OFF_ZP (OFF_FO + BB*PP*4)      // zpart         [B][P][128]
#define OFF_FP (OFF_ZP + BB*PP*ZZ)     // f points      [B][P][K][4] (x,y,z,|f|^2)
#define OFF_GS (OFF_FP + BB*PP*KS*4)   // ground score  [B][P][K][4]
#define OFF_AC (OFF_GS + BB*PP*KS*4)   // loss accumulator [1]

#define CH 1000                        // clean points per LDS chunk
#define NCHK 10                        // chunks (10 * 1000 = M)
#define FINF 1e30f

// ---------------- Stage 1: pack points with squared norms; zero accumulator ----
__global__ void k_pack(const float* __restrict__ noisy, const float* __restrict__ clean,
                       float* __restrict__ ws) {
    int t = blockIdx.x * blockDim.x + threadIdx.x;
    if (t == 0) ws[OFF_AC] = 0.0f;
    const int total = BB*NN + BB*MM;
    if (t >= total) return;
    if (t < BB*NN) {
        float x = noisy[t*3+0], y = noisy[t*3+1], z = noisy[t*3+2];
        float w = (x*x + y*y) + z*z;              // matches jnp.sum(p*p, axis=-1)
        ((float4*)(ws + OFF_PN))[t] = make_float4(x, y, z, w);
    } else {
        int u = t - BB*NN;
        float x = clean[u*3+0], y = clean[u*3+1], z = clean[u*3+2];
        float w = (x*x + y*y) + z*z;
        ((float4*)(ws + OFF_PC))[u] = make_float4(x, y, z, w);
    }
}

// ---------------- Stage 2: per sampled point: f_origin, feat MLP, zpart --------
// one wave per (b,p); 512 waves
__global__ void k_feat(const int* __restrict__ sidx,
                       const float* __restrict__ Wf1, const float* __restrict__ bf1,
                       const float* __restrict__ Wf2, const float* __restrict__ bf2,
                       const float* __restrict__ Ws1, const float* __restrict__ bs1,
                       float* __restrict__ ws) {
    int wave = (blockIdx.x * blockDim.x + threadIdx.x) >> 6;
    int lane = threadIdx.x & 63;
    if (wave >= BB*PP) return;
    int b = wave / PP, p = wave % PP;
    int si = sidx[p];
    float4 q = ((const float4*)(ws + OFF_PN))[b*NN + si];
    if (lane == 0) ((float4*)(ws + OFF_FO))[wave] = q;
    // hidden: relu(p @ Wf1 + bf1)   (64 units, one per lane)
    float h = bf1[lane];
    h = fmaf(q.x, Wf1[0*64 + lane], h);
    h = fmaf(q.y, Wf1[1*64 + lane], h);
    h = fmaf(q.z, Wf1[2*64 + lane], h);
    h = fmaxf(h, 0.0f);
    // feat = h @ Wf2 + bf2  (128 outs, 2 per lane)
    float fa = bf2[lane], fb = bf2[64 + lane];
    for (int i = 0; i < 64; ++i) {
        float hi = __shfl(h, i);
        fa = fmaf(hi, Wf2[i*ZZ + lane],      fa);
        fb = fmaf(hi, Wf2[i*ZZ + 64 + lane], fb);
    }
    // zpart = feat @ Ws1[3:,:] + bs1  (128 outs, 2 per lane)
    float za = bs1[lane], zb = bs1[64 + lane];
    for (int i = 0; i < 64; ++i) {
        float va = __shfl(fa, i);
        float vb = __shfl(fb, i);
        za = fmaf(va, Ws1[(3 + i)*128 + lane],       za);
        zb = fmaf(va, Ws1[(3 + i)*128 + 64 + lane],  zb);
        za = fmaf(vb, Ws1[(67 + i)*128 + lane],      za);
        zb = fmaf(vb, Ws1[(67 + i)*128 + 64 + lane], zb);
    }
    ws[OFF_ZP + wave*ZZ + lane]      = za;
    ws[OFF_ZP + wave*ZZ + 64 + lane] = zb;
}

// ---------------- Stage 3: knn1 — top-32 noisy neighbors of each sampled point -
// one block (256 thr) per (b,p); distances in LDS, 32 argmin-extraction rounds
__global__ __launch_bounds__(256) void k_knn1(const int* __restrict__ sidx, float* __restrict__ ws) {
    __shared__ float dist[NN];
    __shared__ float redv[4];
    __shared__ int   redi[4];
    __shared__ int   winIdx;
    int blk = blockIdx.x;            // = b*P + p
    int b = blk / PP, p = blk % PP;
    int tid = threadIdx.x;
    int si = sidx[p];
    const float4* pts = ((const float4*)(ws + OFF_PN)) + b*NN;
    float4 q = pts[si];
    for (int j = tid; j < NN; j += 256) {
        float4 r = pts[j];
        float dot = fmaf(q.z, r.z, fmaf(q.y, r.y, q.x*r.x));
        dist[j] = fmaf(dot, -2.0f, q.w + r.w);   // (q2+r2) - 2*dot, exact wrt ref
    }
    __syncthreads();
    float m = FINF; int mi = -1;
    for (int j = tid; j < NN; j += 256) {
        float d = dist[j];
        if (d < m) { m = d; mi = j; }
    }
    for (int r = 0; r < KS; ++r) {
        float mm = m; int mmi = mi;
        for (int off = 32; off > 0; off >>= 1) {
            float om = __shfl_down(mm, off);
            int   oi = __shfl_down(mmi, off);
            if (om < mm || (om == mm && oi < mmi)) { mm = om; mmi = oi; }
        }
        if ((tid & 63) == 0) { redv[tid >> 6] = mm; redi[tid >> 6] = mmi; }
        __syncthreads();
        if (tid == 0) {
            float bm = redv[0]; int bi = redi[0];
            for (int w2 = 1; w2 < 4; ++w2)
                if (redv[w2] < bm || (redv[w2] == bm && redi[w2] < bi)) { bm = redv[w2]; bi = redi[w2]; }
            winIdx = bi;
        }
        __syncthreads();
        int wi = winIdx;
        if (tid == 0) ((float4*)(ws + OFF_FP))[blk*KS + r] = pts[wi];
        if (mi == wi) {            // owner re-scans its stride subset
            dist[wi] = FINF;
            m = FINF; mi = -1;
            for (int j = tid; j < NN; j += 256) {
                float d = dist[j];
                if (d < m) { m = d; mi = j; }
            }
        }
        __syncthreads();
    }
}

// ---------------- Stage 4: knn2 — fused exact top-4 + ground score -------------
// 512 blocks x 256 thr. 8 threads/query (in-wave), 32 queries/block.
// Chunks loop INSIDE kernel: per-thread top-4 state persists over its full
// 1250-point stream; chunk-boundary tau-share (query-global exact 4th best)
// makes the insert path rare. LDS broadcast reads are 32-bank conflict-free.
__global__ __launch_bounds__(256) void k_knn2(const float* __restrict__ clean, float* __restrict__ ws) {
    __shared__ float4 sp[CH];
    int tid = threadIdx.x;
    int sub = tid & 7;
    int qi  = tid >> 3;
    int q   = blockIdx.x * 32 + qi;     // global query in [0, B*P*K)
    int b   = q >> 12;                  // P*K = 4096 per batch
    const float4* pts = ((const float4*)(ws + OFF_PC)) + b*MM;
    float4 f4 = ((const float4*)(ws + OFF_FP))[q];
    float fx=f4.x, fy=f4.y, fz=f4.z, f2=f4.w;
    float s0=FINF,s1=FINF,s2=FINF,s3=FINF;
    int   i0=-1,  i1=-1,  i2=-1,  i3=-1;
    float tau = FINF;
    float cut = FINF;
    for (int c = 0; c < NCHK; ++c) {
        __syncthreads();
        for (int u = tid; u < CH; u += 256) sp[u] = pts[c*CH + u];
        __syncthreads();
        int base = c*CH;
        #pragma unroll 5
        for (int t = 0; t < CH/8; ++t) {
            float4 r = sp[t*8 + sub];   // 8 distinct float4 = full 32-bank partition
            float dot = fmaf(fz, r.z, fmaf(fy, r.y, fx*r.x));
            float d = fmaf(dot, -2.0f, f2 + r.w);
            if (d <= cut) {             // <= : keep tau-tie candidates (exactness)
                if (d < s3) {           // strict: thread-local indices increase
                    int jj = base + t*8 + sub;
                    if (d < s2) { s3=s2; i3=i2;
                        if (d < s1) { s2=s1; i2=i1;
                            if (d < s0) { s1=s0; i1=i0; s0=d; i0=jj; }
                            else        { s1=d;  i1=jj; }
                        } else { s2=d; i2=jj; }
                    } else { s3=d; i3=jj; }
                    cut = fminf(tau, s3);
                }
            }
        }
        if (c < NCHK-1) {
            // tau = exact query-global 4th-smallest so far (on copies).
            // Equal-value multi-pop only loosens tau -> still a valid upper bound.
            float a0=s0, a1=s1, a2=s2, a3=s3;
            float m;
            #pragma unroll
            for (int r = 0; r < 4; ++r) {
                m = a0;
                m = fminf(m, __shfl_xor(m, 1));
                m = fminf(m, __shfl_xor(m, 2));
                m = fminf(m, __shfl_xor(m, 4));
                if (a0 == m) { a0=a1; a1=a2; a2=a3; a3=FINF; }
            }
            tau = m;
            cut = fminf(tau, s3);
        }
    }
    // final exact merge of 8 sorted lists, (d, idx)-lexicographic == jax top_k
    float gx = 0.f, gy = 0.f, gz = 0.f;
    int lane = tid & 63;
    for (int r = 0; r < KSC; ++r) {
        float bk = s0; int bi = i0; int bl = lane;
        for (int off = 1; off < 8; off <<= 1) {
            float ok = __shfl_xor(bk, off);
            int   oi = __shfl_xor(bi, off);
            int   ol = __shfl_xor(bl, off);
            if (ok < bk || (ok == bk && oi < bi)) { bk = ok; bi = oi; bl = ol; }
        }
        const float* cp = clean + (size_t)(b*MM + bi)*3;
        gx += cp[0] - fx; gy += cp[1] - fy; gz += cp[2] - fz;
        if (lane == bl) { s0 = s1; i0 = i1; s1 = s2; i1 = i2; s2 = s3; i2 = i3; s3 = FINF; i3 = -1; }
    }
    if (sub == 0) {
        float* gsp = ws + OFF_GS + (size_t)q*4;
        gsp[0] = gx*0.25f; gsp[1] = gy*0.25f; gsp[2] = gz*0.25f;
    }
}

// ---------------- Stage 5: score MLP + loss ------------------------------------
// 64 threads/block, thread-per-f-point; Ws2 staged in LDS (uniform broadcast reads)
__global__ __launch_bounds__(64) void k_mlp(const float* __restrict__ Ws1,
                                            const float* __restrict__ Ws2, const float* __restrict__ bs2,
                                            const float* __restrict__ Ws3, const float* __restrict__ bs3,
                                            float* __restrict__ ws) {
    __shared__ float  sW1[3][128];
    __shared__ float4 sW2[128][16];
    __shared__ float  sB2[64];
    __shared__ float  sW3[64][3];
    __shared__ float  sB3[3];
    __shared__ float  sZP[2][128];
    int tid = threadIdx.x;
    for (int u = tid; u < 384; u += 64) sW1[u >> 7][u & 127] = Ws1[u];
    for (int u = tid; u < 2048; u += 64) ((float4*)sW2)[u] = ((const float4*)Ws2)[u];
    sB2[tid] = bs2[tid];
    for (int u = tid; u < 192; u += 64) ((float*)sW3)[u] = Ws3[u];
    if (tid < 3) sB3[tid] = bs3[tid];
    for (int u = tid; u < 256; u += 64)
        sZP[u >> 7][u & 127] = ws[OFF_ZP + (blockIdx.x*2 + (u >> 7))*ZZ + (u & 127)];
    __syncthreads();

    int g = blockIdx.x*64 + tid;
    float4 f4 = ((const float4*)(ws + OFF_FP))[g];
    float4 fo = ((const float4*)(ws + OFF_FO))[g >> 5];
    float x0 = f4.x - fo.x, x1 = f4.y - fo.y, x2 = f4.z - fo.z;
    const float* zp = sZP[tid >> 5];

    float4 a[16];
    #pragma unroll
    for (int qq = 0; qq < 16; ++qq) a[qq] = make_float4(0.f, 0.f, 0.f, 0.f);

    for (int i = 0; i < 128; ++i) {
        float h1 = fmaf(x2, sW1[2][i], fmaf(x1, sW1[1][i], fmaf(x0, sW1[0][i], zp[i])));
        h1 = fmaxf(h1, 0.0f);
        #pragma unroll
        for (int qq = 0; qq < 16; ++qq) {
            float4 w = sW2[i][qq];
            a[qq].x = fmaf(h1, w.x, a[qq].x);
            a[qq].y = fmaf(h1, w.y, a[qq].y);
            a[qq].z = fmaf(h1, w.z, a[qq].z);
            a[qq].w = fmaf(h1, w.w, a[qq].w);
        }
    }
    float e0 = 0.f, e1 = 0.f, e2 = 0.f;
    #pragma unroll
    for (int qq = 0; qq < 16; ++qq) {
        float av[4] = {a[qq].x, a[qq].y, a[qq].z, a[qq].w};
        #pragma unroll
        for (int c = 0; c < 4; ++c) {
            int j = qq*4 + c;
            float h2 = fmaxf(av[c] + sB2[j], 0.0f);
            e0 = fmaf(h2, sW3[j][0], e0);
            e1 = fmaf(h2, sW3[j][1], e1);
            e2 = fmaf(h2, sW3[j][2], e2);
        }
    }
    e0 += sB3[0]; e1 += sB3[1]; e2 += sB3[2];
    const float* gsp = ws + OFF_GS + (size_t)g*4;
    float d0 = e0 - gsp[0], d1 = e1 - gsp[1], d2 = e2 - gsp[2];
    float t = ((d0*d0 + d1*d1) + d2*d2) * 100.0f;   // 1/SIGMA folds to exactly 100.0f
    for (int off = 32; off > 0; off >>= 1) t += __shfl_down(t, off);
    if (tid == 0) atomicAdd(ws + OFF_AC, t);
}

// ---------------- Stage 6: finalize --------------------------------------------
__global__ void k_fin(const float* __restrict__ ws, float* __restrict__ out) {
    if (threadIdx.x == 0 && blockIdx.x == 0)
        out[0] = ws[OFF_AC] * (1.0f / 32768.0f);    // * 0.5 / (B*P*K), exact pow2
}

extern "C" void kernel_launch(void* const* d_in, const int* in_sizes, int n_in,
                              void* d_out, int out_size, void* d_ws, size_t ws_size,
                              hipStream_t stream) {
    const float* noisy = (const float*)d_in[0];
    const float* clean = (const float*)d_in[1];
    const int*   sidx  = (const int*)  d_in[2];
    const float* Wf1 = (const float*)d_in[3];
    const float* bf1 = (const float*)d_in[4];
    const float* Wf2 = (const float*)d_in[5];
    const float* bf2 = (const float*)d_in[6];
    const float* Ws1 = (const float*)d_in[7];
    const float* bs1 = (const float*)d_in[8];
    const float* Ws2 = (const float*)d_in[9];
    const float* bs2 = (const float*)d_in[10];
    const float* Ws3 = (const float*)d_in[11];
    const float* bs3 = (const float*)d_in[12];
    float* ws  = (float*)d_ws;
    float* out = (float*)d_out;

    k_pack<<<(BB*NN + BB*MM + 255)/256, 256, 0, stream>>>(noisy, clean, ws);
    k_feat<<<(BB*PP*64)/256, 256, 0, stream>>>(sidx, Wf1, bf1, Wf2, bf2, Ws1, bs1, ws);
    k_knn1<<<BB*PP, 256, 0, stream>>>(sidx, ws);
    k_knn2<<<(BB*PP*KS)/32, 256, 0, stream>>>(clean, ws);
    k_mlp<<<(BB*PP*KS)/64, 64, 0, stream>>>(Ws1, Ws2, bs2, Ws3, bs3, ws);
    k_fin<<<1, 64, 0, stream>>>(ws, out);
}

// Round 4
// 276.257 us; speedup vs baseline: 1.1010x; 1.1010x over previous
//
#include <hip/hip_runtime.h>

#define BB 4
#define NN 10000
#define MM 10000
#define PP 128
#define KS 32
#define KSC 4
#define ZZ 128

// workspace layout in floats (all offsets 16B-aligned)
#define OFF_PN 0                       // packed noisy  [B][N][4] (x,y,z,|p|^2)
#define OFF_PC (OFF_PN + BB*NN*4)      // packed clean  [B][M][4] (x,y,z,-|c|^2/2)
#define OFF_FO (OFF_PC + BB*MM*4)      // f_origin      [B][P][4]
#define OFF_ZP (OFF_FO + BB*PP*4)      // zpart         [B][P][128]
#define OFF_FP (OFF_ZP + BB*PP*ZZ)     // f points      [B][P][K][4]
#define OFF_GS (OFF_FP + BB*PP*KS*4)   // ground score  [B][P][K][4]
#define OFF_AC (OFF_GS + BB*PP*KS*4)   // loss accumulator [1]

#define CHK 2000                       // clean points per LDS chunk (5 chunks)
#define FINF 1e30f

// ---------------- Stage 1: pack points; zero accumulator -----------------------
// noisy: w = |p|^2 (knn1 exact formula). clean: w = -|c|^2/2 (e-space for knn2).
__global__ void k_pack(const float* __restrict__ noisy, const float* __restrict__ clean,
                       float* __restrict__ ws) {
    int t = blockIdx.x * blockDim.x + threadIdx.x;
    if (t == 0) ws[OFF_AC] = 0.0f;
    const int total = BB*NN + BB*MM;
    if (t >= total) return;
    if (t < BB*NN) {
        float x = noisy[t*3+0], y = noisy[t*3+1], z = noisy[t*3+2];
        float w = (x*x + y*y) + z*z;
        ((float4*)(ws + OFF_PN))[t] = make_float4(x, y, z, w);
    } else {
        int u = t - BB*NN;
        float x = clean[u*3+0], y = clean[u*3+1], z = clean[u*3+2];
        float w = -0.5f * ((x*x + y*y) + z*z);
        ((float4*)(ws + OFF_PC))[u] = make_float4(x, y, z, w);
    }
}

// ---------------- Stage 2: per sampled point: f_origin, feat MLP, zpart --------
__global__ void k_feat(const int* __restrict__ sidx,
                       const float* __restrict__ Wf1, const float* __restrict__ bf1,
                       const float* __restrict__ Wf2, const float* __restrict__ bf2,
                       const float* __restrict__ Ws1, const float* __restrict__ bs1,
                       float* __restrict__ ws) {
    int wave = (blockIdx.x * blockDim.x + threadIdx.x) >> 6;
    int lane = threadIdx.x & 63;
    if (wave >= BB*PP) return;
    int b = wave / PP, p = wave % PP;
    int si = sidx[p];
    float4 q = ((const float4*)(ws + OFF_PN))[b*NN + si];
    if (lane == 0) ((float4*)(ws + OFF_FO))[wave] = q;
    float h = bf1[lane];
    h = fmaf(q.x, Wf1[0*64 + lane], h);
    h = fmaf(q.y, Wf1[1*64 + lane], h);
    h = fmaf(q.z, Wf1[2*64 + lane], h);
    h = fmaxf(h, 0.0f);
    float fa = bf2[lane], fb = bf2[64 + lane];
    for (int i = 0; i < 64; ++i) {
        float hi = __shfl(h, i);
        fa = fmaf(hi, Wf2[i*ZZ + lane],      fa);
        fb = fmaf(hi, Wf2[i*ZZ + 64 + lane], fb);
    }
    float za = bs1[lane], zb = bs1[64 + lane];
    for (int i = 0; i < 64; ++i) {
        float va = __shfl(fa, i);
        float vb = __shfl(fb, i);
        za = fmaf(va, Ws1[(3 + i)*128 + lane],       za);
        zb = fmaf(va, Ws1[(3 + i)*128 + 64 + lane],  zb);
        za = fmaf(vb, Ws1[(67 + i)*128 + lane],      za);
        zb = fmaf(vb, Ws1[(67 + i)*128 + 64 + lane], zb);
    }
    ws[OFF_ZP + wave*ZZ + lane]      = za;
    ws[OFF_ZP + wave*ZZ + 64 + lane] = zb;
}

// ---------------- Stage 3: knn1 — top-32 noisy neighbors (unchanged) -----------
__global__ __launch_bounds__(256) void k_knn1(const int* __restrict__ sidx, float* __restrict__ ws) {
    __shared__ float dist[NN];
    __shared__ float redv[4];
    __shared__ int   redi[4];
    __shared__ int   winIdx;
    int blk = blockIdx.x;
    int b = blk / PP, p = blk % PP;
    int tid = threadIdx.x;
    int si = sidx[p];
    const float4* pts = ((const float4*)(ws + OFF_PN)) + b*NN;
    float4 q = pts[si];
    for (int j = tid; j < NN; j += 256) {
        float4 r = pts[j];
        float dot = fmaf(q.z, r.z, fmaf(q.y, r.y, q.x*r.x));
        dist[j] = fmaf(dot, -2.0f, q.w + r.w);
    }
    __syncthreads();
    float m = FINF; int mi = -1;
    for (int j = tid; j < NN; j += 256) {
        float d = dist[j];
        if (d < m) { m = d; mi = j; }
    }
    for (int r = 0; r < KS; ++r) {
        float mm = m; int mmi = mi;
        for (int off = 32; off > 0; off >>= 1) {
            float om = __shfl_down(mm, off);
            int   oi = __shfl_down(mmi, off);
            if (om < mm || (om == mm && oi < mmi)) { mm = om; mmi = oi; }
        }
        if ((tid & 63) == 0) { redv[tid >> 6] = mm; redi[tid >> 6] = mmi; }
        __syncthreads();
        if (tid == 0) {
            float bm = redv[0]; int bi = redi[0];
            for (int w2 = 1; w2 < 4; ++w2)
                if (redv[w2] < bm || (redv[w2] == bm && redi[w2] < bi)) { bm = redv[w2]; bi = redi[w2]; }
            winIdx = bi;
        }
        __syncthreads();
        int wi = winIdx;
        if (tid == 0) ((float4*)(ws + OFF_FP))[blk*KS + r] = pts[wi];
        if (mi == wi) {
            dist[wi] = FINF;
            m = FINF; mi = -1;
            for (int j = tid; j < NN; j += 256) {
                float d = dist[j];
                if (d < m) { m = d; mi = j; }
            }
        }
        __syncthreads();
    }
}

// ---------------- Stage 4: knn2 — sample-tau + thresholded exact top-4 ---------
// 512 blocks x 256 thr; 8 subs/query, 32 queries/block. e = dot - |c|^2/2
// (maximize e == minimize d). Phase A: branchless value-only top-4 over chunk 0
// -> tau (4th best; multi-pop only loosens -> safe). Phase B: full rescan,
// gate e >= cmax=max(tau,e3); insert path (exec-masked) fires ~10-20% of iters.
// Exact incl. jax stable tie-break: ascending idx per sub + strict > insert +
// (e,idx)-lex final merge.
__global__ __launch_bounds__(256) void k_knn2(float* __restrict__ ws) {
    __shared__ float4 sp[2][CHK];
    int tid = threadIdx.x;
    int sub = tid & 7;
    int qi  = tid >> 3;
    int q   = blockIdx.x * 32 + qi;
    int b   = q >> 12;                  // P*K = 4096 per batch
    const float4* pts = ((const float4*)(ws + OFF_PC)) + b*MM;
    float4 f4 = ((const float4*)(ws + OFF_FP))[q];
    float fx = f4.x, fy = f4.y, fz = f4.z;

    // stage chunk 0
    for (int u = tid; u < CHK; u += 256) sp[0][u] = pts[u];
    __syncthreads();

    // ---- Phase A: branchless value-only top-4 of chunk 0 (the sample) ----
    float a0 = -FINF, a1 = -FINF, a2 = -FINF, a3 = -FINF;
    for (int t = 0; t < CHK/8; ++t) {
        float4 r = sp[0][t*8 + sub];
        float e = fmaf(fz, r.z, fmaf(fy, r.y, fmaf(fx, r.x, r.w)));
        a3 = fmaxf(a3, fminf(a2, e));   // bottom-up: each uses OLD upper value
        a2 = fmaxf(a2, fminf(a1, e));
        a1 = fmaxf(a1, fminf(a0, e));
        a0 = fmaxf(a0, e);
    }
    float tau;
    {
        float m = 0.0f;
        #pragma unroll
        for (int r = 0; r < 4; ++r) {
            m = a0;
            m = fmaxf(m, __shfl_xor(m, 1));
            m = fmaxf(m, __shfl_xor(m, 2));
            m = fmaxf(m, __shfl_xor(m, 4));
            if (a0 == m) { a0 = a1; a1 = a2; a2 = a3; a3 = -FINF; }
        }
        tau = m;    // >= nothing tighter than true 4th-best e of sample
    }

    // ---- Phase B: exact thresholded scan of ALL 5 chunks ----
    float e0=-FINF, e1=-FINF, e2=-FINF, e3=-FINF;
    int   i0=-1,   i1=-1,   i2=-1,   i3=-1;
    float cmax = tau;

#define INS(EV, JV) \
    if ((EV) > e1) { e3=e2; i3=i2; e2=e1; i2=i1; \
        if ((EV) > e0) { e1=e0; i1=i0; e0=(EV); i0=(JV); } else { e1=(EV); i1=(JV); } \
    } else { \
        if ((EV) > e2) { e3=e2; i3=i2; e2=(EV); i2=(JV); } else { e3=(EV); i3=(JV); } }

#define BSCAN(BUF, BASE) \
    for (int t = 0; t < CHK/8; t += 2) { \
        float4 ra = sp[BUF][t*8 + sub]; \
        float4 rb = sp[BUF][t*8 + 8 + sub]; \
        float ea = fmaf(fz, ra.z, fmaf(fy, ra.y, fmaf(fx, ra.x, ra.w))); \
        float eb = fmaf(fz, rb.z, fmaf(fy, rb.y, fmaf(fx, rb.x, rb.w))); \
        if (fmaxf(ea, eb) >= cmax) { \
            if (ea >= tau && ea > e3) { INS(ea, (BASE) + t*8 + sub); cmax = fmaxf(tau, e3); } \
            if (eb >= tau && eb > e3) { INS(eb, (BASE) + t*8 + 8 + sub); cmax = fmaxf(tau, e3); } \
        } \
    }

    // stage chunk 1 into buf1 (no barrier needed: writes buf1, reads of buf0 ok)
    for (int u = tid; u < CHK; u += 256) sp[1][u] = pts[CHK + u];
    BSCAN(0, 0)                         // chunk 0 (re-scan: sample points included)
    __syncthreads();
    for (int u = tid; u < CHK; u += 256) sp[0][u] = pts[2*CHK + u];
    BSCAN(1, CHK)                       // chunk 1
    __syncthreads();
    for (int u = tid; u < CHK; u += 256) sp[1][u] = pts[3*CHK + u];
    BSCAN(0, 2*CHK)                     // chunk 2
    __syncthreads();
    for (int u = tid; u < CHK; u += 256) sp[0][u] = pts[4*CHK + u];
    BSCAN(1, 3*CHK)                     // chunk 3
    __syncthreads();
    BSCAN(0, 4*CHK)                     // chunk 4

    // ---- final merge of 8 subs, (e desc, idx asc)-lex == jax stable top_k ----
    float gx = 0.f, gy = 0.f, gz = 0.f;
    int lane = tid & 63;
    for (int r = 0; r < KSC; ++r) {
        float bk = e0; int bi = i0; int bl = lane;
        #pragma unroll
        for (int off = 1; off < 8; off <<= 1) {
            float ok = __shfl_xor(bk, off);
            int   oi = __shfl_xor(bi, off);
            int   ol = __shfl_xor(bl, off);
            if (ok > bk || (ok == bk && oi < bi)) { bk = ok; bi = oi; bl = ol; }
        }
        float4 cp = pts[bi];
        gx += cp.x - fx; gy += cp.y - fy; gz += cp.z - fz;
        if (lane == bl) { e0 = e1; i0 = i1; e1 = e2; i1 = i2; e2 = e3; i2 = i3; e3 = -FINF; i3 = -1; }
    }
    if (sub == 0) {
        float* gsp = ws + OFF_GS + (size_t)q*4;
        gsp[0] = gx*0.25f; gsp[1] = gy*0.25f; gsp[2] = gz*0.25f;
    }
}

// ---------------- Stage 5: score MLP + loss (unchanged) ------------------------
__global__ __launch_bounds__(64) void k_mlp(const float* __restrict__ Ws1,
                                            const float* __restrict__ Ws2, const float* __restrict__ bs2,
                                            const float* __restrict__ Ws3, const float* __restrict__ bs3,
                                            float* __restrict__ ws) {
    __shared__ float  sW1[3][128];
    __shared__ float4 sW2[128][16];
    __shared__ float  sB2[64];
    __shared__ float  sW3[64][3];
    __shared__ float  sB3[3];
    __shared__ float  sZP[2][128];
    int tid = threadIdx.x;
    for (int u = tid; u < 384; u += 64) sW1[u >> 7][u & 127] = Ws1[u];
    for (int u = tid; u < 2048; u += 64) ((float4*)sW2)[u] = ((const float4*)Ws2)[u];
    sB2[tid] = bs2[tid];
    for (int u = tid; u < 192; u += 64) ((float*)sW3)[u] = Ws3[u];
    if (tid < 3) sB3[tid] = bs3[tid];
    for (int u = tid; u < 256; u += 64)
        sZP[u >> 7][u & 127] = ws[OFF_ZP + (blockIdx.x*2 + (u >> 7))*ZZ + (u & 127)];
    __syncthreads();

    int g = blockIdx.x*64 + tid;
    float4 f4 = ((const float4*)(ws + OFF_FP))[g];
    float4 fo = ((const float4*)(ws + OFF_FO))[g >> 5];
    float x0 = f4.x - fo.x, x1 = f4.y - fo.y, x2 = f4.z - fo.z;
    const float* zp = sZP[tid >> 5];

    float4 a[16];
    #pragma unroll
    for (int qq = 0; qq < 16; ++qq) a[qq] = make_float4(0.f, 0.f, 0.f, 0.f);

    for (int i = 0; i < 128; ++i) {
        float h1 = fmaf(x2, sW1[2][i], fmaf(x1, sW1[1][i], fmaf(x0, sW1[0][i], zp[i])));
        h1 = fmaxf(h1, 0.0f);
        #pragma unroll
        for (int qq = 0; qq < 16; ++qq) {
            float4 w = sW2[i][qq];
            a[qq].x = fmaf(h1, w.x, a[qq].x);
            a[qq].y = fmaf(h1, w.y, a[qq].y);
            a[qq].z = fmaf(h1, w.z, a[qq].z);
            a[qq].w = fmaf(h1, w.w, a[qq].w);
        }
    }
    float e0 = 0.f, e1 = 0.f, e2 = 0.f;
    #pragma unroll
    for (int qq = 0; qq < 16; ++qq) {
        float av[4] = {a[qq].x, a[qq].y, a[qq].z, a[qq].w};
        #pragma unroll
        for (int c = 0; c < 4; ++c) {
            int j = qq*4 + c;
            float h2 = fmaxf(av[c] + sB2[j], 0.0f);
            e0 = fmaf(h2, sW3[j][0], e0);
            e1 = fmaf(h2, sW3[j][1], e1);
            e2 = fmaf(h2, sW3[j][2], e2);
        }
    }
    e0 += sB3[0]; e1 += sB3[1]; e2 += sB3[2];
    const float* gsp = ws + OFF_GS + (size_t)g*4;
    float d0 = e0 - gsp[0], d1 = e1 - gsp[1], d2 = e2 - gsp[2];
    float t = ((d0*d0 + d1*d1) + d2*d2) * 100.0f;
    for (int off = 32; off > 0; off >>= 1) t += __shfl_down(t, off);
    if (tid == 0) atomicAdd(ws + OFF_AC, t);
}

// ---------------- Stage 6: finalize --------------------------------------------
__global__ void k_fin(const float* __restrict__ ws, float* __restrict__ out) {
    if (threadIdx.x == 0 && blockIdx.x == 0)
        out[0] = ws[OFF_AC] * (1.0f / 32768.0f);
}

extern "C" void kernel_launch(void* const* d_in, const int* in_sizes, int n_in,
                              void* d_out, int out_size, void* d_ws, size_t ws_size,
                              hipStream_t stream) {
    const float* noisy = (const float*)d_in[0];
    const float* clean = (const float*)d_in[1];
    const int*   sidx  = (const int*)  d_in[2];
    const float* Wf1 = (const float*)d_in[3];
    const float* bf1 = (const float*)d_in[4];
    const float* Wf2 = (const float*)d_in[5];
    const float* bf2 = (const float*)d_in[6];
    const float* Ws1 = (const float*)d_in[7];
    const float* bs1 = (const float*)d_in[8];
    const float* Ws2 = (const float*)d_in[9];
    const float* bs2 = (const float*)d_in[10];
    const float* Ws3 = (const float*)d_in[11];
    const float* bs3 = (const float*)d_in[12];
    float* ws  = (float*)d_ws;
    float* out = (float*)d_out;

    k_pack<<<(BB*NN + BB*MM + 255)/256, 256, 0, stream>>>(noisy, clean, ws);
    k_feat<<<(BB*PP*64)/256, 256, 0, stream>>>(sidx, Wf1, bf1, Wf2, bf2, Ws1, bs1, ws);
    k_knn1<<<BB*PP, 256, 0, stream>>>(sidx, ws);
    k_knn2<<<(BB*PP*KS)/32, 256, 0, stream>>>(ws);
    k_mlp<<<(BB*PP*KS)/64, 64, 0, stream>>>(Ws1, Ws2, bs2, Ws3, bs3, ws);
    k_fin<<<1, 64, 0, stream>>>(ws, out);
}